// Round 6
// baseline (118.955 us; speedup 1.0000x reference)
//
#include <hip/hip_runtime.h>
#include <math.h>

#define NQ 14
#define DIM (1 << NQ)      // 16384 amplitudes
#define NT 1024            // 16 waves per block
#define TA 16              // amplitudes per thread (4-bit tile)
#define NW (NT / 64)

// State tile in ext_vectors -> first-class SSA, never alloca'd.
typedef float v16f __attribute__((ext_vector_type(16)));

// Bank swizzle on float2-index: phys = idx ^ ((idx>>5)&31). Linear under XOR.
__host__ __device__ constexpr int swz(int idx) { return idx ^ ((idx >> 5) & 31); }

// Conditional base-XOR masks (swizzled), all verified:
// swz(0x2000)=0x2000 (bit13), swz(0x3C0)=0x3DE (bits9..6), swz(0x3C)=0x3D (bits5..2)
#define SWZ_B13  0x2000
#define SWZ_CH9  0x3DE
#define SWZ_CH5  0x3D

// Tile over 4 bit positions: local bit k of j lives at global bit Pk.
// Non-tile bits get tid bits scattered ascending.
template <int P0, int P1, int P2, int P3>
struct Tile4 {
    static constexpr int PMASK = (1 << P0) | (1 << P1) | (1 << P2) | (1 << P3);
    static __device__ __forceinline__ int base_idx(int t) {
        int idx = 0, tb = 0;
#pragma unroll
        for (int p = 0; p < NQ; ++p)
            if (!((PMASK >> p) & 1)) { idx |= ((t >> tb) & 1) << p; ++tb; }
        return idx;
    }
    static constexpr int off(int j) {
        return ((j & 1) << P0) | (((j >> 1) & 1) << P1) |
               (((j >> 2) & 1) << P2) | (((j >> 3) & 1) << P3);
    }
};

// Rounds (bit q of state at position 13-q):
using TileA = Tile4<10, 11, 12, 13>;  // r1: locals 3..0 = bits 13,12,11,10 = q0..q3
using TileB = Tile4<6, 7, 8, 9>;      // r2: locals 3..0 = bits 9,8,7,6    = q4..q7
using TileC = Tile4<2, 3, 4, 5>;      // r3: locals 3..0 = bits 5,4,3,2    = q8..q11
using TileD = Tile4<0, 1, 2, 3>;      // r4: locals 1,0  = bits 1,0        = q12,q13

// Compile-time index maps implementing folded CNOT chains (new[P(i)] = old[i]):
struct MapId    { static constexpr int map(int j) { return j; } };
// 3 (or 4 w/ cond base-XOR) descending chain links on locals 3->0:
// l3'=l3, l2'=l2^l3, l1'=l1^l2^l3, l0'=l0^l1^l2^l3
struct MapChain {
    static constexpr int map(int j) {
        const int j0 = j & 1, j1 = (j >> 1) & 1, j2 = (j >> 2) & 1, j3 = (j >> 3) & 1;
        return (j0 ^ j1 ^ j2 ^ j3) | ((j1 ^ j2 ^ j3) << 1) | ((j2 ^ j3) << 2) | (j3 << 3);
    }
};
// r4: CNOT(2,1) then (1,0): l1'=l1^l2, l0'=l0^l1^l2
struct MapR4 {
    static constexpr int map(int j) {
        const int j0 = j & 1, j1 = (j >> 1) & 1, j2 = (j >> 2) & 1, j3 = (j >> 3) & 1;
        return (j0 ^ j1 ^ j2) | ((j1 ^ j2) << 1) | (j2 << 2) | (j3 << 3);
    }
};

template <class T>
__device__ __forceinline__ void load_tile(const float2* s, int pb, v16f& re, v16f& im) {
#pragma unroll
    for (int j = 0; j < TA; ++j) {
        float2 v = s[pb ^ swz(T::off(j))];
        re[j] = v.x; im[j] = v.y;
    }
}
template <class T, class M>
__device__ __forceinline__ void store_tile(float2* s, int pb, v16f re, v16f im) {
#pragma unroll
    for (int j = 0; j < TA; ++j)
        s[pb ^ swz(T::off(M::map(j)))] = make_float2(re[j], im[j]);
}

// RY: [[c,-s],[s,c]] on local bit LB
template <int LB>
__device__ __forceinline__ void g_ry(v16f& re, v16f& im, float c, float s) {
#pragma unroll
    for (int j = 0; j < TA; ++j) {
        if (j & (1 << LB)) continue;
        const int k = j | (1 << LB);
        float r0 = re[j], i0 = im[j], r1 = re[k], i1 = im[k];
        re[j] = c * r0 - s * r1;  im[j] = c * i0 - s * i1;
        re[k] = s * r0 + c * r1;  im[k] = s * i0 + c * i1;
    }
}
// RX: [[c,-is],[-is,c]]
template <int LB>
__device__ __forceinline__ void g_rx(v16f& re, v16f& im, float c, float s) {
#pragma unroll
    for (int j = 0; j < TA; ++j) {
        if (j & (1 << LB)) continue;
        const int k = j | (1 << LB);
        float r0 = re[j], i0 = im[j], r1 = re[k], i1 = im[k];
        re[j] = c * r0 + s * i1;  im[j] = c * i0 - s * r1;
        re[k] = c * r1 + s * i0;  im[k] = c * i1 - s * r0;
    }
}

// Per layer, 4 rounds. All CNOTs fold into addressing:
//  r1 store: (q0,q1)(q1,q2)(q2,q3) -> MapChain
//  r2 store: (q3,q4) -> base^=(tid bit6)?SWZ_CH9 ; (q4,q5)(q5,q6)(q6,q7) -> MapChain
//  r3 store: (q7,q8) -> base^=(tid bit2)?SWZ_CH5 ; (q8,q9)(q9,q10)(q10,q11) -> MapChain
//  r4 store: (q11,q12)(q12,q13) -> MapR4
//  (q13,q0): next layer's r1 load base^=(tid bit0)?SWZ_B13; last layer: epilogue signs.
__global__ void __launch_bounds__(NT) qsim_kernel(const float* __restrict__ x,
                                                  const float* __restrict__ w,
                                                  float* __restrict__ out) {
    __shared__ float2 sSt[DIM];          // 128 KB
    __shared__ float sC[56], sS[56];     // [0..13]=RY embed, 14+l*14+q = RX
    __shared__ float sRed[NW][NQ];

    const int tid = threadIdx.x;
    const int b = blockIdx.x;

    if (tid < 14) {
        float th = tanhf(x[b * NQ + tid]) * 1.57079632679489662f;
        sC[tid] = cosf(th); sS[tid] = sinf(th);
    } else if (tid < 56) {
        float th = w[tid - 14] * 0.5f;
        sC[tid] = cosf(th); sS[tid] = sinf(th);
    }

    // Precompute swizzled bases (tid-fixed, reused across layers)
    const int pbA = swz(TileA::base_idx(tid));
    const int pbA_ld = pbA ^ ((tid & 1) ? SWZ_B13 : 0);        // folds (q13,q0)
    const int pbB = swz(TileB::base_idx(tid));
    const int pbB_st = pbB ^ ((tid & 0x40) ? SWZ_CH9 : 0);     // folds (q3,q4)
    const int pbC = swz(TileC::base_idx(tid));
    const int pbC_st = pbC ^ ((tid & 4) ? SWZ_CH5 : 0);        // folds (q7,q8)
    const int pbD = swz(TileD::base_idx(tid));

    __syncthreads();

    v16f re, im;

    // ================= layer 0 (embedding folded in) =================
    {   // r1: init |0..0> + RY q0-3 + RX q0-3
#pragma unroll
        for (int j = 0; j < TA; ++j) { re[j] = 0.f; im[j] = 0.f; }
        if (tid == 0) re[0] = 1.f;
        g_ry<3>(re, im, sC[0], sS[0]);  g_ry<2>(re, im, sC[1], sS[1]);
        g_ry<1>(re, im, sC[2], sS[2]);  g_ry<0>(re, im, sC[3], sS[3]);
        g_rx<3>(re, im, sC[14], sS[14]); g_rx<2>(re, im, sC[15], sS[15]);
        g_rx<1>(re, im, sC[16], sS[16]); g_rx<0>(re, im, sC[17], sS[17]);
        store_tile<TileA, MapChain>(sSt, pbA, re, im);
    }
    __syncthreads();
    {   // r2: RY q4-7 + RX q4-7
        load_tile<TileB>(sSt, pbB, re, im);
        g_ry<3>(re, im, sC[4], sS[4]);  g_ry<2>(re, im, sC[5], sS[5]);
        g_ry<1>(re, im, sC[6], sS[6]);  g_ry<0>(re, im, sC[7], sS[7]);
        g_rx<3>(re, im, sC[18], sS[18]); g_rx<2>(re, im, sC[19], sS[19]);
        g_rx<1>(re, im, sC[20], sS[20]); g_rx<0>(re, im, sC[21], sS[21]);
        store_tile<TileB, MapChain>(sSt, pbB_st, re, im);
    }
    __syncthreads();
    {   // r3: RY q8-11 + RX q8-11
        load_tile<TileC>(sSt, pbC, re, im);
        g_ry<3>(re, im, sC[8], sS[8]);   g_ry<2>(re, im, sC[9], sS[9]);
        g_ry<1>(re, im, sC[10], sS[10]); g_ry<0>(re, im, sC[11], sS[11]);
        g_rx<3>(re, im, sC[22], sS[22]); g_rx<2>(re, im, sC[23], sS[23]);
        g_rx<1>(re, im, sC[24], sS[24]); g_rx<0>(re, im, sC[25], sS[25]);
        store_tile<TileC, MapChain>(sSt, pbC_st, re, im);
    }
    __syncthreads();
    {   // r4: RY q12,13 + RX q12,13
        load_tile<TileD>(sSt, pbD, re, im);
        g_ry<1>(re, im, sC[12], sS[12]); g_ry<0>(re, im, sC[13], sS[13]);
        g_rx<1>(re, im, sC[26], sS[26]); g_rx<0>(re, im, sC[27], sS[27]);
        store_tile<TileD, MapR4>(sSt, pbD, re, im);
    }
    __syncthreads();

    // ================= layers 1,2 =================
#pragma unroll 1
    for (int l = 1; l < 3; ++l) {
        const int s0 = 14 + l * NQ;
        {   // r1 (load folds previous layer's (q13,q0))
            load_tile<TileA>(sSt, pbA_ld, re, im);
            g_rx<3>(re, im, sC[s0 + 0], sS[s0 + 0]); g_rx<2>(re, im, sC[s0 + 1], sS[s0 + 1]);
            g_rx<1>(re, im, sC[s0 + 2], sS[s0 + 2]); g_rx<0>(re, im, sC[s0 + 3], sS[s0 + 3]);
            store_tile<TileA, MapChain>(sSt, pbA, re, im);
        }
        __syncthreads();
        {   // r2
            load_tile<TileB>(sSt, pbB, re, im);
            g_rx<3>(re, im, sC[s0 + 4], sS[s0 + 4]); g_rx<2>(re, im, sC[s0 + 5], sS[s0 + 5]);
            g_rx<1>(re, im, sC[s0 + 6], sS[s0 + 6]); g_rx<0>(re, im, sC[s0 + 7], sS[s0 + 7]);
            store_tile<TileB, MapChain>(sSt, pbB_st, re, im);
        }
        __syncthreads();
        {   // r3
            load_tile<TileC>(sSt, pbC, re, im);
            g_rx<3>(re, im, sC[s0 + 8], sS[s0 + 8]);   g_rx<2>(re, im, sC[s0 + 9], sS[s0 + 9]);
            g_rx<1>(re, im, sC[s0 + 10], sS[s0 + 10]); g_rx<0>(re, im, sC[s0 + 11], sS[s0 + 11]);
            store_tile<TileC, MapChain>(sSt, pbC_st, re, im);
        }
        __syncthreads();
        {   // r4
            load_tile<TileD>(sSt, pbD, re, im);
            g_rx<1>(re, im, sC[s0 + 12], sS[s0 + 12]); g_rx<0>(re, im, sC[s0 + 13], sS[s0 + 13]);
            if (l == 1) { store_tile<TileD, MapR4>(sSt, pbD, re, im); }
        }
        if (l == 1) __syncthreads();
    }

    // ====== expvals (tile D regs; virtual (q11,q12),(q12,q13),(q13,q0) folds) ======
    // eff bit1 = j1^j2 (q12), eff bit0 = j0^j1^j2 (q13), eff bit13 = t9 ^ eff bit0 (q0)
    float Stot = 0.f, Aacc = 0.f, Bacc = 0.f, Cacc = 0.f, Eacc = 0.f;
#pragma unroll
    for (int j = 0; j < TA; ++j) {
        float pj = re[j] * re[j] + im[j] * im[j];
        Stot += pj;
        Aacc += (j & 8) ? -pj : pj;                               // bit3  -> q10
        Bacc += (j & 4) ? -pj : pj;                               // bit2  -> q11
        Cacc += (((j >> 1) ^ (j >> 2)) & 1) ? -pj : pj;           // j1^j2 -> q12
        Eacc += ((j ^ (j >> 1) ^ (j >> 2)) & 1) ? -pj : pj;       // j0^j1^j2 -> q13 (and q0)
    }
    float ev[NQ];
    ev[0]  = (tid & 512) ? -Eacc : Eacc;   // q0:  t9 ^ (j0^j1^j2)
#pragma unroll
    for (int q = 1; q <= 9; ++q) {         // q1..q9 -> bits 12..4 = tid bits 8..0
        const int tb = 13 - q - 4;
        ev[q] = ((tid >> tb) & 1) ? -Stot : Stot;
    }
    ev[10] = Aacc; ev[11] = Bacc; ev[12] = Cacc; ev[13] = Eacc;

#pragma unroll
    for (int q = 0; q < NQ; ++q) {
#pragma unroll
        for (int o = 32; o > 0; o >>= 1) ev[q] += __shfl_down(ev[q], o);
    }
    const int wv = tid >> 6, ln = tid & 63;
    if (ln == 0) {
#pragma unroll
        for (int q = 0; q < NQ; ++q) sRed[wv][q] = ev[q];
    }
    __syncthreads();
    if (tid < NQ) {
        float acc = 0.f;
#pragma unroll
        for (int k = 0; k < NW; ++k) acc += sRed[k][tid];
        out[b * NQ + tid] = acc;
    }
}

extern "C" void kernel_launch(void* const* d_in, const int* in_sizes, int n_in,
                              void* d_out, int out_size, void* d_ws, size_t ws_size,
                              hipStream_t stream) {
    const float* x = (const float*)d_in[0];   // (256, 14) float32
    const float* w = (const float*)d_in[1];   // (3, 14) float32
    float* out = (float*)d_out;               // (256, 14) float32
    qsim_kernel<<<256, NT, 0, stream>>>(x, w, out);
}

// Round 7
// 90.670 us; speedup vs baseline: 1.3120x; 1.3120x over previous
//
#include <hip/hip_runtime.h>
#include <math.h>

#define NQ 14
#define DIM (1 << NQ)      // 16384 amplitudes
#define NT 512             // 8 waves per block -> 2 waves/SIMD -> 256-VGPR budget
#define TA 32              // amplitudes per thread (5-bit tile)
#define NW (NT / 64)

// State tile in ext_vectors -> first-class SSA, never alloca'd.
typedef float v32f __attribute__((ext_vector_type(32)));

// Bank swizzle on float2-index: phys = idx ^ ((idx>>5)&31). Linear under XOR.
// Verified: all four round tiles below give each bank-pair exactly 4 lanes
// (the wave64 minimum) for every unrolled j.
__host__ __device__ constexpr int swz(int idx) { return idx ^ ((idx >> 5) & 31); }

// Tile over 5 bit positions: local bit k of j lives at global bit Pk.
// Non-tile bits get tid bits scattered ascending.
template <int P0, int P1, int P2, int P3, int P4>
struct Tile5 {
    static constexpr int PMASK = (1 << P0) | (1 << P1) | (1 << P2) | (1 << P3) | (1 << P4);
    static __device__ __forceinline__ int base_idx(int t) {
        int idx = 0, tb = 0;
#pragma unroll
        for (int p = 0; p < NQ; ++p)
            if (!((PMASK >> p) & 1)) { idx |= ((t >> tb) & 1) << p; ++tb; }
        return idx;
    }
    static constexpr int off(int j) {
        return ((j & 1) << P0) | (((j >> 1) & 1) << P1) | (((j >> 2) & 1) << P2) |
               (((j >> 3) & 1) << P3) | (((j >> 4) & 1) << P4);
    }
};

// qubit q lives at bit position 13-q.
using TileR1 = Tile5<9, 10, 11, 12, 13>;   // l4..l0 = q0,q1,q2,q3,q4
using TileR2 = Tile5<5, 6, 7, 8, 9>;       // l4..l0 = q4,q5,q6,q7,q8
using TileR3 = Tile5<1, 2, 3, 4, 5>;       // l4..l0 = q8,q9,q10,q11,q12
using TileR4 = Tile5<0, 1, 13, 12, 11>;    // l0=q13, l1=q12, l2=q0, l3=q1, l4=q2

template <class T>
__device__ __forceinline__ void load_tile(const float2* s, int pb, v32f& re, v32f& im) {
#pragma unroll
    for (int j = 0; j < TA; ++j) {
        float2 v = s[pb ^ swz(T::off(j))];
        re[j] = v.x; im[j] = v.y;
    }
}
template <class T>
__device__ __forceinline__ void store_tile(float2* s, int pb, v32f re, v32f im) {
#pragma unroll
    for (int j = 0; j < TA; ++j)
        s[pb ^ swz(T::off(j))] = make_float2(re[j], im[j]);
}

// RY: [[c,-s],[s,c]] on local bit LB (register-only)
template <int LB>
__device__ __forceinline__ void g_ry(v32f& re, v32f& im, float c, float s) {
#pragma unroll
    for (int j = 0; j < TA; ++j) {
        if (j & (1 << LB)) continue;
        const int k = j | (1 << LB);
        float r0 = re[j], i0 = im[j], r1 = re[k], i1 = im[k];
        re[j] = c * r0 - s * r1;  im[j] = c * i0 - s * i1;
        re[k] = s * r0 + c * r1;  im[k] = s * i0 + c * i1;
    }
}
// RX: [[c,-is],[-is,c]]
template <int LB>
__device__ __forceinline__ void g_rx(v32f& re, v32f& im, float c, float s) {
#pragma unroll
    for (int j = 0; j < TA; ++j) {
        if (j & (1 << LB)) continue;
        const int k = j | (1 << LB);
        float r0 = re[j], i0 = im[j], r1 = re[k], i1 = im[k];
        re[j] = c * r0 + s * i1;  im[j] = c * i0 - s * r1;
        re[k] = c * r1 + s * i0;  im[k] = c * i1 - s * r0;
    }
}
// CNOT control local LC, target local LT: pure register permutation
template <int LC, int LT>
__device__ __forceinline__ void g_cnot(v32f& re, v32f& im) {
#pragma unroll
    for (int j = 0; j < TA; ++j) {
        if (!((j >> LC) & 1) || ((j >> LT) & 1)) continue;
        const int k = j | (1 << LT);
        float tr = re[j], ti = im[j];
        re[j] = re[k]; im[j] = im[k];
        re[k] = tr;    im[k] = ti;
    }
}

// Per layer, 4 rounds (ring CNOTs in order (q0,q1)..(q12,q13)(q13,q0)):
//  R1 {q0..q4}:  RX q0-4,  CNOT(q0,q1)(q1,q2)(q2,q3)(q3,q4)
//  R2 {q4..q8}:  RX q5-8,  CNOT(q4,q5)(q5,q6)(q6,q7)(q7,q8)
//  R3 {q8..q12}: RX q9-12, CNOT(q8,q9)(q9,q10)(q10,q11)(q11,q12)
//  R4 {q13,q12,q0,q1,q2}: RX q13, CNOT(q12,q13)(q13,q0)
// Embedding RYs folded into layer-0's rounds (commute with gates on other
// qubits; per-qubit RY precedes RX within its round).
__global__ void __launch_bounds__(NT, 2) qsim_kernel(const float* __restrict__ x,
                                                     const float* __restrict__ w,
                                                     float* __restrict__ out) {
    __shared__ float2 sSt[DIM];          // 128 KB
    __shared__ float sC[56], sS[56];     // [0..13]=RY embed, 14+l*14+q = RX
    __shared__ float sRed[NW][NQ];

    const int tid = threadIdx.x;
    const int b = blockIdx.x;

    if (tid < 14) {
        float th = tanhf(x[b * NQ + tid]) * 1.57079632679489662f;
        sC[tid] = cosf(th); sS[tid] = sinf(th);
    } else if (tid < 56) {
        float th = w[tid - 14] * 0.5f;
        sC[tid] = cosf(th); sS[tid] = sinf(th);
    }

    const int pb1 = swz(TileR1::base_idx(tid));
    const int pb2 = swz(TileR2::base_idx(tid));
    const int pb3 = swz(TileR3::base_idx(tid));
    const int pb4 = swz(TileR4::base_idx(tid));

    __syncthreads();

    v32f re, im;

    // ================= layer 0 (embedding folded in) =================
    {   // R1: init |0..0> + RY q0-4 + RX q0-4 + chain CNOTs
#pragma unroll
        for (int j = 0; j < TA; ++j) { re[j] = 0.f; im[j] = 0.f; }
        if (tid == 0) re[0] = 1.f;
        g_ry<4>(re, im, sC[0], sS[0]);  g_ry<3>(re, im, sC[1], sS[1]);
        g_ry<2>(re, im, sC[2], sS[2]);  g_ry<1>(re, im, sC[3], sS[3]);
        g_ry<0>(re, im, sC[4], sS[4]);
        g_rx<4>(re, im, sC[14], sS[14]); g_rx<3>(re, im, sC[15], sS[15]);
        g_rx<2>(re, im, sC[16], sS[16]); g_rx<1>(re, im, sC[17], sS[17]);
        g_rx<0>(re, im, sC[18], sS[18]);
        g_cnot<4, 3>(re, im); g_cnot<3, 2>(re, im);
        g_cnot<2, 1>(re, im); g_cnot<1, 0>(re, im);
        store_tile<TileR1>(sSt, pb1, re, im);
    }
    __syncthreads();
    {   // R2: RY q5-8 + RX q5-8 + CNOT(q4,q5)..(q7,q8)
        load_tile<TileR2>(sSt, pb2, re, im);
        g_ry<3>(re, im, sC[5], sS[5]);  g_ry<2>(re, im, sC[6], sS[6]);
        g_ry<1>(re, im, sC[7], sS[7]);  g_ry<0>(re, im, sC[8], sS[8]);
        g_rx<3>(re, im, sC[19], sS[19]); g_rx<2>(re, im, sC[20], sS[20]);
        g_rx<1>(re, im, sC[21], sS[21]); g_rx<0>(re, im, sC[22], sS[22]);
        g_cnot<4, 3>(re, im); g_cnot<3, 2>(re, im);
        g_cnot<2, 1>(re, im); g_cnot<1, 0>(re, im);
        store_tile<TileR2>(sSt, pb2, re, im);
    }
    __syncthreads();
    {   // R3: RY q9-12 + RX q9-12 + CNOT(q8,q9)..(q11,q12)
        load_tile<TileR3>(sSt, pb3, re, im);
        g_ry<3>(re, im, sC[9], sS[9]);   g_ry<2>(re, im, sC[10], sS[10]);
        g_ry<1>(re, im, sC[11], sS[11]); g_ry<0>(re, im, sC[12], sS[12]);
        g_rx<3>(re, im, sC[23], sS[23]); g_rx<2>(re, im, sC[24], sS[24]);
        g_rx<1>(re, im, sC[25], sS[25]); g_rx<0>(re, im, sC[26], sS[26]);
        g_cnot<4, 3>(re, im); g_cnot<3, 2>(re, im);
        g_cnot<2, 1>(re, im); g_cnot<1, 0>(re, im);
        store_tile<TileR3>(sSt, pb3, re, im);
    }
    __syncthreads();
    {   // R4: RY q13 + RX q13 + CNOT(q12,q13)(q13,q0)
        load_tile<TileR4>(sSt, pb4, re, im);
        g_ry<0>(re, im, sC[13], sS[13]);
        g_rx<0>(re, im, sC[27], sS[27]);
        g_cnot<1, 0>(re, im); g_cnot<0, 2>(re, im);
        store_tile<TileR4>(sSt, pb4, re, im);
    }
    __syncthreads();

    // ================= layers 1,2 =================
#pragma unroll 1
    for (int l = 1; l < 3; ++l) {
        const int s0 = 14 + l * NQ;
        {   // R1
            load_tile<TileR1>(sSt, pb1, re, im);
            g_rx<4>(re, im, sC[s0 + 0], sS[s0 + 0]); g_rx<3>(re, im, sC[s0 + 1], sS[s0 + 1]);
            g_rx<2>(re, im, sC[s0 + 2], sS[s0 + 2]); g_rx<1>(re, im, sC[s0 + 3], sS[s0 + 3]);
            g_rx<0>(re, im, sC[s0 + 4], sS[s0 + 4]);
            g_cnot<4, 3>(re, im); g_cnot<3, 2>(re, im);
            g_cnot<2, 1>(re, im); g_cnot<1, 0>(re, im);
            store_tile<TileR1>(sSt, pb1, re, im);
        }
        __syncthreads();
        {   // R2
            load_tile<TileR2>(sSt, pb2, re, im);
            g_rx<3>(re, im, sC[s0 + 5], sS[s0 + 5]); g_rx<2>(re, im, sC[s0 + 6], sS[s0 + 6]);
            g_rx<1>(re, im, sC[s0 + 7], sS[s0 + 7]); g_rx<0>(re, im, sC[s0 + 8], sS[s0 + 8]);
            g_cnot<4, 3>(re, im); g_cnot<3, 2>(re, im);
            g_cnot<2, 1>(re, im); g_cnot<1, 0>(re, im);
            store_tile<TileR2>(sSt, pb2, re, im);
        }
        __syncthreads();
        {   // R3
            load_tile<TileR3>(sSt, pb3, re, im);
            g_rx<3>(re, im, sC[s0 + 9], sS[s0 + 9]);   g_rx<2>(re, im, sC[s0 + 10], sS[s0 + 10]);
            g_rx<1>(re, im, sC[s0 + 11], sS[s0 + 11]); g_rx<0>(re, im, sC[s0 + 12], sS[s0 + 12]);
            g_cnot<4, 3>(re, im); g_cnot<3, 2>(re, im);
            g_cnot<2, 1>(re, im); g_cnot<1, 0>(re, im);
            store_tile<TileR3>(sSt, pb3, re, im);
        }
        __syncthreads();
        {   // R4
            load_tile<TileR4>(sSt, pb4, re, im);
            g_rx<0>(re, im, sC[s0 + 13], sS[s0 + 13]);
            g_cnot<1, 0>(re, im); g_cnot<0, 2>(re, im);
            if (l == 1) store_tile<TileR4>(sSt, pb4, re, im);
        }
        if (l == 1) __syncthreads();
    }

    // ====== expvals from final registers (TileR4: l0=q13,l1=q12,l2=q0,l3=q1,l4=q2) ======
    float Stot = 0.f, S0 = 0.f, S1 = 0.f, S2 = 0.f, S3 = 0.f, S4 = 0.f;
#pragma unroll
    for (int j = 0; j < TA; ++j) {
        float pj = re[j] * re[j] + im[j] * im[j];
        Stot += pj;
        S0 += (j & 1)  ? -pj : pj;   // q13
        S1 += (j & 2)  ? -pj : pj;   // q12
        S2 += (j & 4)  ? -pj : pj;   // q0
        S3 += (j & 8)  ? -pj : pj;   // q1
        S4 += (j & 16) ? -pj : pj;   // q2
    }
    float ev[NQ];
    ev[0] = S2; ev[1] = S3; ev[2] = S4; ev[12] = S1; ev[13] = S0;
#pragma unroll
    for (int q = 3; q <= 11; ++q)    // q3..q11 <- tid bit (11-q)
        ev[q] = ((tid >> (11 - q)) & 1) ? -Stot : Stot;

#pragma unroll
    for (int q = 0; q < NQ; ++q) {
#pragma unroll
        for (int o = 32; o > 0; o >>= 1) ev[q] += __shfl_down(ev[q], o);
    }
    const int wv = tid >> 6, ln = tid & 63;
    if (ln == 0) {
#pragma unroll
        for (int q = 0; q < NQ; ++q) sRed[wv][q] = ev[q];
    }
    __syncthreads();
    if (tid < NQ) {
        float acc = 0.f;
#pragma unroll
        for (int k = 0; k < NW; ++k) acc += sRed[k][tid];
        out[b * NQ + tid] = acc;
    }
}

extern "C" void kernel_launch(void* const* d_in, const int* in_sizes, int n_in,
                              void* d_out, int out_size, void* d_ws, size_t ws_size,
                              hipStream_t stream) {
    const float* x = (const float*)d_in[0];   // (256, 14) float32
    const float* w = (const float*)d_in[1];   // (3, 14) float32
    float* out = (float*)d_out;               // (256, 14) float32
    qsim_kernel<<<256, NT, 0, stream>>>(x, w, out);
}

// Round 8
// 87.794 us; speedup vs baseline: 1.3549x; 1.0328x over previous
//
#include <hip/hip_runtime.h>
#include <math.h>

#define NQ 14
#define DIM (1 << NQ)      // 16384 amplitudes
#define NT 512             // 8 waves per block; 129 KB LDS -> 1 block/CU -> 2 waves/EU
#define TA 32              // amplitudes per thread (5-bit tile)
#define NW (NT / 64)

// State: ONE interleaved ext_vector (re,im at 2j,2j+1) -> SSA, never alloca'd,
// and LDS b64 accesses map directly onto adjacent VGPR pairs (no repack movs).
typedef float v64f __attribute__((ext_vector_type(64)));
typedef float cf2  __attribute__((ext_vector_type(2)));   // (re, im)

__device__ __forceinline__ cf2 getc(const v64f& a, int j) {
    cf2 r; r.x = a[2 * j]; r.y = a[2 * j + 1]; return r;
}
__device__ __forceinline__ void putc_(v64f& a, int j, cf2 v) {
    a[2 * j] = v.x; a[2 * j + 1] = v.y;
}
__device__ __forceinline__ cf2 swapneg(cf2 v) {   // (x,y) -> (y,-x)  [= -i * conj-swap]
    cf2 r; r.x = v.y; r.y = -v.x; return r;
}

// Bank swizzle on cf2-index: phys = idx ^ ((idx>>5)&31). Linear under XOR.
// Verified: all four round tiles give each bank-pair exactly 4 lanes per
// unrolled j (the wave64 minimum) -> conflict-minimal b64.
__host__ __device__ constexpr int swz(int idx) { return idx ^ ((idx >> 5) & 31); }

// Tile over 5 bit positions: local bit k of j lives at global bit Pk.
// Non-tile bits get tid bits scattered ascending.
template <int P0, int P1, int P2, int P3, int P4>
struct Tile5 {
    static constexpr int PMASK = (1 << P0) | (1 << P1) | (1 << P2) | (1 << P3) | (1 << P4);
    static __device__ __forceinline__ int base_idx(int t) {
        int idx = 0, tb = 0;
#pragma unroll
        for (int p = 0; p < NQ; ++p)
            if (!((PMASK >> p) & 1)) { idx |= ((t >> tb) & 1) << p; ++tb; }
        return idx;
    }
    static constexpr int off(int j) {
        return ((j & 1) << P0) | (((j >> 1) & 1) << P1) | (((j >> 2) & 1) << P2) |
               (((j >> 3) & 1) << P3) | (((j >> 4) & 1) << P4);
    }
};

// qubit q lives at bit position 13-q.
using TileR1 = Tile5<9, 10, 11, 12, 13>;   // l4..l0 = q0,q1,q2,q3,q4
using TileR2 = Tile5<5, 6, 7, 8, 9>;       // l4..l0 = q4,q5,q6,q7,q8
using TileR3 = Tile5<1, 2, 3, 4, 5>;       // l4..l0 = q8,q9,q10,q11,q12
using TileR4 = Tile5<0, 1, 13, 12, 11>;    // l0=q13, l1=q12, l2=q0, l3=q1, l4=q2

template <class T>
__device__ __forceinline__ void load_tile(const cf2* s, int pb, v64f& a) {
#pragma unroll
    for (int j = 0; j < TA; ++j)
        putc_(a, j, s[pb ^ swz(T::off(j))]);
}
template <class T>
__device__ __forceinline__ void store_tile(cf2* s, int pb, const v64f& a) {
#pragma unroll
    for (int j = 0; j < TA; ++j)
        s[pb ^ swz(T::off(j))] = getc(a, j);
}

// RY: [[c,-s],[s,c]] — pure 2-lane SIMD: aj' = c*aj - s*ak ; ak' = s*aj + c*ak
template <int LB>
__device__ __forceinline__ void g_ry(v64f& a, float c, float s) {
#pragma unroll
    for (int j = 0; j < TA; ++j) {
        if (j & (1 << LB)) continue;
        const int k = j | (1 << LB);
        cf2 aj = getc(a, j), ak = getc(a, k);
        putc_(a, j, c * aj - s * ak);
        putc_(a, k, s * aj + c * ak);
    }
}
// RX: [[c,-is],[-is,c]] — aj' = c*aj + s*swapneg(ak) ; ak' = c*ak + s*swapneg(aj)
template <int LB>
__device__ __forceinline__ void g_rx(v64f& a, float c, float s) {
#pragma unroll
    for (int j = 0; j < TA; ++j) {
        if (j & (1 << LB)) continue;
        const int k = j | (1 << LB);
        cf2 aj = getc(a, j), ak = getc(a, k);
        putc_(a, j, c * aj + s * swapneg(ak));
        putc_(a, k, c * ak + s * swapneg(aj));
    }
}
// CNOT control local LC, target local LT: pure register permutation
template <int LC, int LT>
__device__ __forceinline__ void g_cnot(v64f& a) {
#pragma unroll
    for (int j = 0; j < TA; ++j) {
        if (!((j >> LC) & 1) || ((j >> LT) & 1)) continue;
        const int k = j | (1 << LT);
        cf2 t = getc(a, j);
        putc_(a, j, getc(a, k));
        putc_(a, k, t);
    }
}

// Per layer, 4 rounds (ring CNOTs in order (q0,q1)..(q12,q13)(q13,q0)):
//  R1 {q0..q4}:  RX q0-4,  CNOT(q0,q1)(q1,q2)(q2,q3)(q3,q4)
//  R2 {q4..q8}:  RX q5-8,  CNOT(q4,q5)(q5,q6)(q6,q7)(q7,q8)
//  R3 {q8..q12}: RX q9-12, CNOT(q8,q9)(q9,q10)(q10,q11)(q11,q12)
//  R4 {q13,q12,q0,q1,q2}: RX q13, CNOT(q12,q13)(q13,q0)
// Embedding RYs folded into layer-0's rounds.
//
// amdgpu_waves_per_eu(2,2): occupancy is 1 block/CU anyway (129 KB LDS), so
// declare exactly 2 waves/EU -> VGPR cap 256 -> stop the allocator's
// fixed-occupancy heuristic that clamped to 128 and spilled ~18 regs (the
// 9.2 MB WRITE_SIZE in r7).
__attribute__((amdgpu_waves_per_eu(2, 2)))
__global__ void __launch_bounds__(NT) qsim_kernel(const float* __restrict__ x,
                                                  const float* __restrict__ w,
                                                  float* __restrict__ out) {
    __shared__ cf2 sSt[DIM];             // 128 KB
    __shared__ float sC[56], sS[56];     // [0..13]=RY embed, 14+l*14+q = RX
    __shared__ float sRed[NW][NQ];

    const int tid = threadIdx.x;
    const int b = blockIdx.x;

    if (tid < 14) {
        float th = tanhf(x[b * NQ + tid]) * 1.57079632679489662f;
        sC[tid] = cosf(th); sS[tid] = sinf(th);
    } else if (tid < 56) {
        float th = w[tid - 14] * 0.5f;
        sC[tid] = cosf(th); sS[tid] = sinf(th);
    }

    const int pb1 = swz(TileR1::base_idx(tid));
    const int pb2 = swz(TileR2::base_idx(tid));
    const int pb3 = swz(TileR3::base_idx(tid));
    const int pb4 = swz(TileR4::base_idx(tid));

    __syncthreads();

    v64f a;

    // ================= layer 0 (embedding folded in) =================
    {   // R1: init |0..0> + RY q0-4 + RX q0-4 + chain CNOTs
#pragma unroll
        for (int j = 0; j < 2 * TA; ++j) a[j] = 0.f;
        if (tid == 0) a[0] = 1.f;
        g_ry<4>(a, sC[0], sS[0]);  g_ry<3>(a, sC[1], sS[1]);
        g_ry<2>(a, sC[2], sS[2]);  g_ry<1>(a, sC[3], sS[3]);
        g_ry<0>(a, sC[4], sS[4]);
        g_rx<4>(a, sC[14], sS[14]); g_rx<3>(a, sC[15], sS[15]);
        g_rx<2>(a, sC[16], sS[16]); g_rx<1>(a, sC[17], sS[17]);
        g_rx<0>(a, sC[18], sS[18]);
        g_cnot<4, 3>(a); g_cnot<3, 2>(a); g_cnot<2, 1>(a); g_cnot<1, 0>(a);
        store_tile<TileR1>(sSt, pb1, a);
    }
    __syncthreads();
    {   // R2: RY q5-8 + RX q5-8 + CNOT(q4,q5)..(q7,q8)
        load_tile<TileR2>(sSt, pb2, a);
        g_ry<3>(a, sC[5], sS[5]);  g_ry<2>(a, sC[6], sS[6]);
        g_ry<1>(a, sC[7], sS[7]);  g_ry<0>(a, sC[8], sS[8]);
        g_rx<3>(a, sC[19], sS[19]); g_rx<2>(a, sC[20], sS[20]);
        g_rx<1>(a, sC[21], sS[21]); g_rx<0>(a, sC[22], sS[22]);
        g_cnot<4, 3>(a); g_cnot<3, 2>(a); g_cnot<2, 1>(a); g_cnot<1, 0>(a);
        store_tile<TileR2>(sSt, pb2, a);
    }
    __syncthreads();
    {   // R3: RY q9-12 + RX q9-12 + CNOT(q8,q9)..(q11,q12)
        load_tile<TileR3>(sSt, pb3, a);
        g_ry<3>(a, sC[9], sS[9]);   g_ry<2>(a, sC[10], sS[10]);
        g_ry<1>(a, sC[11], sS[11]); g_ry<0>(a, sC[12], sS[12]);
        g_rx<3>(a, sC[23], sS[23]); g_rx<2>(a, sC[24], sS[24]);
        g_rx<1>(a, sC[25], sS[25]); g_rx<0>(a, sC[26], sS[26]);
        g_cnot<4, 3>(a); g_cnot<3, 2>(a); g_cnot<2, 1>(a); g_cnot<1, 0>(a);
        store_tile<TileR3>(sSt, pb3, a);
    }
    __syncthreads();
    {   // R4: RY q13 + RX q13 + CNOT(q12,q13)(q13,q0)
        load_tile<TileR4>(sSt, pb4, a);
        g_ry<0>(a, sC[13], sS[13]);
        g_rx<0>(a, sC[27], sS[27]);
        g_cnot<1, 0>(a); g_cnot<0, 2>(a);
        store_tile<TileR4>(sSt, pb4, a);
    }
    __syncthreads();

    // ================= layers 1,2 =================
#pragma unroll 1
    for (int l = 1; l < 3; ++l) {
        const int s0 = 14 + l * NQ;
        {   // R1
            load_tile<TileR1>(sSt, pb1, a);
            g_rx<4>(a, sC[s0 + 0], sS[s0 + 0]); g_rx<3>(a, sC[s0 + 1], sS[s0 + 1]);
            g_rx<2>(a, sC[s0 + 2], sS[s0 + 2]); g_rx<1>(a, sC[s0 + 3], sS[s0 + 3]);
            g_rx<0>(a, sC[s0 + 4], sS[s0 + 4]);
            g_cnot<4, 3>(a); g_cnot<3, 2>(a); g_cnot<2, 1>(a); g_cnot<1, 0>(a);
            store_tile<TileR1>(sSt, pb1, a);
        }
        __syncthreads();
        {   // R2
            load_tile<TileR2>(sSt, pb2, a);
            g_rx<3>(a, sC[s0 + 5], sS[s0 + 5]); g_rx<2>(a, sC[s0 + 6], sS[s0 + 6]);
            g_rx<1>(a, sC[s0 + 7], sS[s0 + 7]); g_rx<0>(a, sC[s0 + 8], sS[s0 + 8]);
            g_cnot<4, 3>(a); g_cnot<3, 2>(a); g_cnot<2, 1>(a); g_cnot<1, 0>(a);
            store_tile<TileR2>(sSt, pb2, a);
        }
        __syncthreads();
        {   // R3
            load_tile<TileR3>(sSt, pb3, a);
            g_rx<3>(a, sC[s0 + 9], sS[s0 + 9]);   g_rx<2>(a, sC[s0 + 10], sS[s0 + 10]);
            g_rx<1>(a, sC[s0 + 11], sS[s0 + 11]); g_rx<0>(a, sC[s0 + 12], sS[s0 + 12]);
            g_cnot<4, 3>(a); g_cnot<3, 2>(a); g_cnot<2, 1>(a); g_cnot<1, 0>(a);
            store_tile<TileR3>(sSt, pb3, a);
        }
        __syncthreads();
        {   // R4
            load_tile<TileR4>(sSt, pb4, a);
            g_rx<0>(a, sC[s0 + 13], sS[s0 + 13]);
            g_cnot<1, 0>(a); g_cnot<0, 2>(a);
            if (l == 1) store_tile<TileR4>(sSt, pb4, a);
        }
        if (l == 1) __syncthreads();
    }

    // ====== expvals from final registers (TileR4: l0=q13,l1=q12,l2=q0,l3=q1,l4=q2) ======
    float Stot = 0.f, S0 = 0.f, S1 = 0.f, S2 = 0.f, S3 = 0.f, S4 = 0.f;
#pragma unroll
    for (int j = 0; j < TA; ++j) {
        cf2 v = getc(a, j);
        float pj = v.x * v.x + v.y * v.y;
        Stot += pj;
        S0 += (j & 1)  ? -pj : pj;   // q13
        S1 += (j & 2)  ? -pj : pj;   // q12
        S2 += (j & 4)  ? -pj : pj;   // q0
        S3 += (j & 8)  ? -pj : pj;   // q1
        S4 += (j & 16) ? -pj : pj;   // q2
    }
    float ev[NQ];
    ev[0] = S2; ev[1] = S3; ev[2] = S4; ev[12] = S1; ev[13] = S0;
#pragma unroll
    for (int q = 3; q <= 11; ++q)    // q3..q11 <- tid bit (11-q)
        ev[q] = ((tid >> (11 - q)) & 1) ? -Stot : Stot;

#pragma unroll
    for (int q = 0; q < NQ; ++q) {
#pragma unroll
        for (int o = 32; o > 0; o >>= 1) ev[q] += __shfl_down(ev[q], o);
    }
    const int wv = tid >> 6, ln = tid & 63;
    if (ln == 0) {
#pragma unroll
        for (int q = 0; q < NQ; ++q) sRed[wv][q] = ev[q];
    }
    __syncthreads();
    if (tid < NQ) {
        float acc = 0.f;
#pragma unroll
        for (int k = 0; k < NW; ++k) acc += sRed[k][tid];
        out[b * NQ + tid] = acc;
    }
}

extern "C" void kernel_launch(void* const* d_in, const int* in_sizes, int n_in,
                              void* d_out, int out_size, void* d_ws, size_t ws_size,
                              hipStream_t stream) {
    const float* x = (const float*)d_in[0];   // (256, 14) float32
    const float* w = (const float*)d_in[1];   // (3, 14) float32
    float* out = (float*)d_out;               // (256, 14) float32
    qsim_kernel<<<256, NT, 0, stream>>>(x, w, out);
}